// Round 4
// baseline (97.455 us; speedup 1.0000x reference)
//
#include <hip/hip_runtime.h>
#include <math.h>

namespace {

constexpr int   MTOT   = 4096;       // total nodes
constexpr float H      = 0.1f;

// W_FACTORS = sqrt((0.5^2 + sigma^2)/2), sigma in {0.4, 0.8, 1.2, 1.6}
constexpr float W0 = 0.45276925690687087f;
constexpr float W1 = 0.66708320320631664f;
constexpr float W2 = 0.91923881554251174f;
constexpr float W3 = 1.18532695911296985f;

constexpr float KCOUL   = 14.399645478425669f;  // e*1e10/eps0/(4*pi)
constexpr float HALF_L1 = 2.8867513459481287f;  // 0.5*sqrt(3)/0.3
constexpr float SQRTPI  = 1.7724538509055159f;

// pk_r = 0.47047*(0.5/W_r) ;  c2_r = -(0.5/W_r)^2 * log2(e)
constexpr float PK0 = 0.5195472f, PK1 = 0.3526314f, PK2 = 0.2559019f, PK3 = 0.1984558f;
constexpr float C20 = -1.7593842f, C21 = -0.8105028f, C22 = -0.4268329f, C23 = -0.2567073f;
// A&S 7.1.25 coefficients (|err| <= 2.5e-5); a1+a2+a3 == 1 -> erf(0)=0
constexpr float EA1 = 0.3480242f, EA2 = -0.0958798f, EA3 = 0.7478556f;

// 1/(ds + 1e-6) for ds = h, h*sqrt2, 2h
constexpr float RCP_H   = 9.9999000f;
constexpr float RCP_HS2 = 7.0710178f;
constexpr float RCP_2H  = 4.9999750f;

__device__ __forceinline__ float fast_rcp(float x)  { return __builtin_amdgcn_rcpf(x); }
__device__ __forceinline__ float fast_rsq(float x)  { return __builtin_amdgcn_rsqf(x); }
__device__ __forceinline__ float fast_exp2(float x) { return __builtin_amdgcn_exp2f(x); }

// q(x) = erfc(k*d) approx = (a1 t + a2 t^2 + a3 t^3) * e^{-(kd)^2}, t = 1/(1+p*k*d)
__device__ __forceinline__ float erf_q(float d, float d2, float pk, float c2) {
  float t = fast_rcp(__builtin_fmaf(d, pk, 1.0f));
  float poly = t * __builtin_fmaf(t, __builtin_fmaf(t, EA3, EA2), EA1);
  return poly * fast_exp2(d2 * c2);
}

// project (7 x 4) site-features S[j*4+r] -> 16 outputs
__device__ __forceinline__ float project_one(const float* S, int k) {
  if (k < 4) return S[k];
  int q = k - 4;
  int r = q / 3;
  int comp = q - 3 * r;
  int j1, j2;
  if (comp == 0)      { j1 = 2; j2 = 5; }
  else if (comp == 1) { j1 = 3; j2 = 6; }
  else                { j1 = 1; j2 = 4; }
  return HALF_L1 * (S[j1 * 4 + r] - S[j2 * 4 + r]);
}

// grid: 512 blocks = 32 graphs x 16 site-blocks (56 target sites = 8 nodes each)
// block: 448 threads (7 waves) = 56 sites x 8 source-chunks of 112
// LDS ~23 KB -> 4 blocks/CU co-resident (28 waves, 87.5% occupancy)
__global__ __launch_bounds__(448, 7) void es_main(
    const float* __restrict__ sf,   // (4096, 4)
    const float* __restrict__ pos,  // (4096, 3)
    float* __restrict__ out)        // [0:65536) features, [65536:131072) self_terms
{
  __shared__ float4 s_site[896];     // whole graph's sites: xyz + charge
  __shared__ float4 s_part[8 * 56];  // per-chunk partial (a0..a3) per target site
  __shared__ float  s_feat[56 * 4];  // per-site features
  __shared__ float  s_self[56 * 4];  // per-site self term

  const int b   = blockIdx.x;
  const int g   = b >> 4;    // graph
  const int sb  = b & 15;    // site-block: sites [sb*56, sb*56+56) of graph
  const int tid = threadIdx.x;

  // ---- stage all 896 sites of this graph (2 sites/thread) ----
  for (int s = tid; s < 896; s += 448) {
    const int i  = (s * 9363) >> 16;   // s/7 (exact for s < 896)
    const int bb = s - i * 7;
    const int node = g * 128 + i;
    float px = pos[node * 3 + 0];
    float py = pos[node * 3 + 1];
    float pz = pos[node * 3 + 2];
    float ch;
    if (bb == 0) {
      ch = sf[node * 4 + 0];
    } else {
      int ax = (bb - 1) % 3;                 // 0:x 1:y 2:z
      int comp = (ax == 0) ? 3 : ax;         // b1/b4 -> s3, b2/b5 -> s1, b3/b6 -> s2
      float sgn = (bb >= 4) ? -5.0f : 5.0f;  // 1/(2h), negated for back offsets
      ch = sf[node * 4 + comp] * sgn;
      float o = (bb >= 4) ? -H : H;
      if (ax == 0)      px += o;
      else if (ax == 1) py += o;
      else              pz += o;
    }
    s_site[s] = make_float4(px, py, pz, ch);
  }
  __syncthreads();

  // ---- main pair loop: thread = (target site, source chunk) ----
  const int site_local = tid % 56;
  const int chunk      = tid / 56;
  const int sl         = sb * 56 + site_local;   // target site within graph
  const float4 t4 = s_site[sl];
  const int src_base  = chunk * 112;
  const int cmp_local = sl - src_base;  // own-site index within this chunk (may be OOR)

  float S = 0.f, q0 = 0.f, q1 = 0.f, q2 = 0.f, q3 = 0.f;
  for (int it0 = 0; it0 < 112; it0 += 14) {
    const int tgt = cmp_local - it0;
#pragma unroll
    for (int u = 0; u < 14; ++u) {
      float4 s4 = s_site[src_base + it0 + u];  // <=2 distinct addrs per wave: broadcast
      float dx = t4.x - s4.x;
      float dy = t4.y - s4.y;
      float dz = t4.z - s4.z;
      float d2 = __builtin_fmaf(dx, dx, 1e-12f);
      d2 = __builtin_fmaf(dy, dy, d2);
      d2 = __builtin_fmaf(dz, dz, d2);
      float rd = fast_rsq(d2);
      float d  = d2 * rd;
      float cv = (u == tgt) ? 0.0f : s4.w * rd;  // mask only the singular own-site pair
      S += cv;
      q0 = __builtin_fmaf(cv, erf_q(d, d2, PK0, C20), q0);
      q1 = __builtin_fmaf(cv, erf_q(d, d2, PK1, C21), q1);
      q2 = __builtin_fmaf(cv, erf_q(d, d2, PK2, C22), q2);
      q3 = __builtin_fmaf(cv, erf_q(d, d2, PK3, C23), q3);
    }
  }
  s_part[chunk * 56 + site_local] = make_float4(S - q0, S - q1, S - q2, S - q3);
  __syncthreads();

  // ---- reduce chunks + self term + own-node correction (cancels to +c_a*diag) ----
  if (tid < 224) {
    const int site = tid >> 2;   // 0..55
    const int r    = tid & 3;
    const float* pf = (const float*)s_part;
    float tot = 0.f;
#pragma unroll
    for (int c = 0; c < 8; ++c) tot += pf[c * 224 + tid];  // stride 224 % 32 == 0: conflict-free

    const float w  = (r == 0) ? W0  : (r == 1) ? W1  : (r == 2) ? W2  : W3;
    const float pk = (r == 0) ? PK0 : (r == 1) ? PK1 : (r == 2) ? PK2 : PK3;
    const float c2 = (r == 0) ? C20 : (r == 1) ? C21 : (r == 2) ? C22 : C23;
    const float diag = fast_rcp(w * SQRTPI);
    const float ph1 = (1.f - erf_q(0.1f,        0.01f, pk, c2)) * RCP_H;
    const float ph2 = (1.f - erf_q(0.14142136f, 0.02f, pk, c2)) * RCP_HS2;
    const float ph3 = (1.f - erf_q(0.2f,        0.04f, pk, c2)) * RCP_2H;

    const int jn = (site * 9363) >> 16;  // node within this site-block (0..7)
    const int ba = site - jn * 7;        // this site's offset index
    const int cbase = sb * 56 + jn * 7;  // node's 7 sites in s_site
    float selfSum = 0.f, ca = 0.f;
#pragma unroll
    for (int i = 0; i < 7; ++i) {
      float ci = s_site[cbase + i].w;
      float ph;
      if (i == ba)                             ph = diag;
      else if (i == 0 || ba == 0)              ph = ph1;
      else if ((i - ba == 3) || (ba - i == 3)) ph = ph3;
      else                                     ph = ph2;
      selfSum = __builtin_fmaf(ci, ph, selfSum);
      if (i == ba) ca = ci;
    }
    // features(site) = K*(tot - ownNodeOffDiag) + K*selfSum = K*(tot + c_a*diag)
    s_self[tid] = KCOUL * selfSum;
    s_feat[tid] = KCOUL * __builtin_fmaf(ca, diag, tot);
  }
  __syncthreads();

  // ---- projection + coalesced write (8 nodes x 16 outputs) ----
  if (tid < 128) {
    const int nl = tid >> 4;
    const int k  = tid & 15;
    const int m  = g * 128 + sb * 8 + nl;
    float vf = project_one(&s_feat[nl * 28], k);
    float vs = project_one(&s_self[nl * 28], k);
    out[m * 16 + k]             = vf;
    out[MTOT * 16 + m * 16 + k] = vs;
  }
}

} // namespace

extern "C" void kernel_launch(void* const* d_in, const int* in_sizes, int n_in,
                              void* d_out, int out_size, void* d_ws, size_t ws_size,
                              hipStream_t stream) {
  const float* sf  = (const float*)d_in[0];   // source_feats (4096,1,4)
  const float* pos = (const float*)d_in[1];   // node_positions (4096,3)
  float* out = (float*)d_out;
  es_main<<<512, 448, 0, stream>>>(sf, pos, out);
}

// Round 5
// 96.749 us; speedup vs baseline: 1.0073x; 1.0073x over previous
//
#include <hip/hip_runtime.h>
#include <math.h>

namespace {

constexpr int   MTOT   = 4096;       // total nodes
constexpr float H      = 0.1f;

// W_FACTORS = sqrt((0.5^2 + sigma^2)/2), sigma in {0.4, 0.8, 1.2, 1.6}
constexpr float W0 = 0.45276925690687087f;
constexpr float W1 = 0.66708320320631664f;
constexpr float W2 = 0.91923881554251174f;
constexpr float W3 = 1.18532695911296985f;

constexpr float KCOUL   = 14.399645478425669f;  // e*1e10/eps0/(4*pi)
constexpr float HALF_L1 = 2.8867513459481287f;  // 0.5*sqrt(3)/0.3
constexpr float SQRTPI  = 1.7724538509055159f;

// pk_r = 0.47047*(0.5/W_r) ;  c2_r = -(0.5/W_r)^2 * log2(e)
constexpr float PK0 = 0.5195472f, PK1 = 0.3526314f, PK2 = 0.2559019f, PK3 = 0.1984558f;
constexpr float C20 = -1.7593842f, C21 = -0.8105028f, C22 = -0.4268329f, C23 = -0.2567073f;
// A&S 7.1.25 coefficients (|err| <= 2.5e-5); a1+a2+a3 == 1 -> erf(0)=0
constexpr float EA1 = 0.3480242f, EA2 = -0.0958798f, EA3 = 0.7478556f;

// 1/(ds + 1e-6) for ds = h, h*sqrt2, 2h
constexpr float RCP_H   = 9.9999000f;
constexpr float RCP_HS2 = 7.0710178f;
constexpr float RCP_2H  = 4.9999750f;

__device__ __forceinline__ float fast_rcp(float x)  { return __builtin_amdgcn_rcpf(x); }
__device__ __forceinline__ float fast_rsq(float x)  { return __builtin_amdgcn_rsqf(x); }
__device__ __forceinline__ float fast_exp2(float x) { return __builtin_amdgcn_exp2f(x); }

// q(x) = erfc-part: (a1 t + a2 t^2 + a3 t^3) * e^{-(kd)^2}, t = 1/(1+p*k*d)
__device__ __forceinline__ float erf_q(float d, float d2, float pk, float c2) {
  float t = fast_rcp(__builtin_fmaf(d, pk, 1.0f));
  float poly = t * __builtin_fmaf(t, __builtin_fmaf(t, EA3, EA2), EA1);
  return poly * fast_exp2(d2 * c2);
}

// project (7 x 4) site-features S[j*4+r] -> 16 outputs
__device__ __forceinline__ float project_one(const float* S, int k) {
  if (k < 4) return S[k];
  int q = k - 4;
  int r = q / 3;
  int comp = q - 3 * r;
  int j1, j2;
  if (comp == 0)      { j1 = 2; j2 = 5; }
  else if (comp == 1) { j1 = 3; j2 = 6; }
  else                { j1 = 1; j2 = 4; }
  return HALF_L1 * (S[j1 * 4 + r] - S[j2 * 4 + r]);
}

// grid: 1024 blocks = 32 graphs x 32 site-blocks (28 target sites = 4 nodes each)
// block: 448 threads (7 waves) = 28 sites x 16 source-chunks of 56
// 1024 blocks / 256 CU = exactly 4 blocks/CU = 28 waves/CU (87.5% occupancy)
// LDS ~22.4 KB/block -> 4 co-resident fits (89.6 KB < 160 KB)
__global__ __launch_bounds__(448, 7) void es_main(
    const float* __restrict__ sf,   // (4096, 4)
    const float* __restrict__ pos,  // (4096, 3)
    float* __restrict__ out)        // [0:65536) features, [65536:131072) self_terms
{
  __shared__ float4 s_site[896];      // whole graph's sites: xyz + charge
  __shared__ float4 s_part[16 * 28];  // per-chunk partial (a0..a3) per target site
  __shared__ float  s_feat[28 * 4];   // per-site features
  __shared__ float  s_self[28 * 4];   // per-site self term

  const int b   = blockIdx.x;
  const int g   = b >> 5;    // graph
  const int sbk = b & 31;    // site-block: sites [sbk*28, sbk*28+28) of graph
  const int tid = threadIdx.x;

  // ---- stage all 896 sites of this graph (2 sites/thread) ----
  for (int s = tid; s < 896; s += 448) {
    const int i  = (s * 9363) >> 16;   // s/7 (exact for s < 896)
    const int bb = s - i * 7;
    const int node = g * 128 + i;
    float px = pos[node * 3 + 0];
    float py = pos[node * 3 + 1];
    float pz = pos[node * 3 + 2];
    float ch;
    if (bb == 0) {
      ch = sf[node * 4 + 0];
    } else {
      int ax = (bb - 1) % 3;                 // 0:x 1:y 2:z
      int comp = (ax == 0) ? 3 : ax;         // b1/b4 -> s3, b2/b5 -> s1, b3/b6 -> s2
      float sgn = (bb >= 4) ? -5.0f : 5.0f;  // 1/(2h), negated for back offsets
      ch = sf[node * 4 + comp] * sgn;
      float o = (bb >= 4) ? -H : H;
      if (ax == 0)      px += o;
      else if (ax == 1) py += o;
      else              pz += o;
    }
    s_site[s] = make_float4(px, py, pz, ch);
  }
  __syncthreads();

  // ---- main pair loop: thread = (target site, source chunk of 56) ----
  const int chunk      = tid / 28;        // 0..15
  const int site_local = tid - chunk * 28;
  const int sl         = sbk * 28 + site_local;   // target site within graph
  const float4 t4 = s_site[sl];
  const int src_base  = chunk * 56;
  const int cmp_local = sl - src_base;  // own-site index within this chunk (may be OOR)

  float S = 0.f, q0 = 0.f, q1 = 0.f, q2 = 0.f, q3 = 0.f;
  for (int it0 = 0; it0 < 56; it0 += 14) {
    const int tgt = cmp_local - it0;
#pragma unroll
    for (int u = 0; u < 14; ++u) {
      float4 s4 = s_site[src_base + it0 + u];  // <=3 distinct addrs per wave: broadcast
      float dx = t4.x - s4.x;
      float dy = t4.y - s4.y;
      float dz = t4.z - s4.z;
      float d2 = __builtin_fmaf(dx, dx, 1e-12f);
      d2 = __builtin_fmaf(dy, dy, d2);
      d2 = __builtin_fmaf(dz, dz, d2);
      float rd = fast_rsq(d2);
      float d  = d2 * rd;
      float cv = (u == tgt) ? 0.0f : s4.w * rd;  // mask only the singular own-site pair
      S += cv;
      q0 = __builtin_fmaf(cv, erf_q(d, d2, PK0, C20), q0);
      q1 = __builtin_fmaf(cv, erf_q(d, d2, PK1, C21), q1);
      q2 = __builtin_fmaf(cv, erf_q(d, d2, PK2, C22), q2);
      q3 = __builtin_fmaf(cv, erf_q(d, d2, PK3, C23), q3);
    }
  }
  s_part[chunk * 28 + site_local] = make_float4(S - q0, S - q1, S - q2, S - q3);
  __syncthreads();

  // ---- reduce chunks + self term + own-node correction (cancels to +c_a*diag) ----
  if (tid < 112) {
    const int site = tid >> 2;   // 0..27
    const int r    = tid & 3;
    const float* pf = (const float*)s_part;
    float tot = 0.f;
#pragma unroll
    for (int c = 0; c < 16; ++c) tot += pf[c * 112 + tid];  // consecutive lanes: conflict-free

    const float w  = (r == 0) ? W0  : (r == 1) ? W1  : (r == 2) ? W2  : W3;
    const float pk = (r == 0) ? PK0 : (r == 1) ? PK1 : (r == 2) ? PK2 : PK3;
    const float c2 = (r == 0) ? C20 : (r == 1) ? C21 : (r == 2) ? C22 : C23;
    const float diag = fast_rcp(w * SQRTPI);
    const float ph1 = (1.f - erf_q(0.1f,        0.01f, pk, c2)) * RCP_H;
    const float ph2 = (1.f - erf_q(0.14142136f, 0.02f, pk, c2)) * RCP_HS2;
    const float ph3 = (1.f - erf_q(0.2f,        0.04f, pk, c2)) * RCP_2H;

    const int jn = (site * 9363) >> 16;  // node within this site-block (0..3)
    const int ba = site - jn * 7;        // this site's offset index
    const int cbase = sbk * 28 + jn * 7; // node's 7 sites in s_site
    float selfSum = 0.f, ca = 0.f;
#pragma unroll
    for (int i = 0; i < 7; ++i) {
      float ci = s_site[cbase + i].w;
      float ph;
      if (i == ba)                             ph = diag;
      else if (i == 0 || ba == 0)              ph = ph1;
      else if ((i - ba == 3) || (ba - i == 3)) ph = ph3;
      else                                     ph = ph2;
      selfSum = __builtin_fmaf(ci, ph, selfSum);
      if (i == ba) ca = ci;
    }
    // features(site) = K*(tot - ownNodeOffDiag) + K*selfSum = K*(tot + c_a*diag)
    s_self[tid] = KCOUL * selfSum;
    s_feat[tid] = KCOUL * __builtin_fmaf(ca, diag, tot);
  }
  __syncthreads();

  // ---- projection + coalesced write (4 nodes x 16 outputs) ----
  if (tid < 64) {
    const int nl = tid >> 4;
    const int k  = tid & 15;
    const int m  = g * 128 + sbk * 4 + nl;
    float vf = project_one(&s_feat[nl * 28], k);
    float vs = project_one(&s_self[nl * 28], k);
    out[m * 16 + k]             = vf;
    out[MTOT * 16 + m * 16 + k] = vs;
  }
}

} // namespace

extern "C" void kernel_launch(void* const* d_in, const int* in_sizes, int n_in,
                              void* d_out, int out_size, void* d_ws, size_t ws_size,
                              hipStream_t stream) {
  const float* sf  = (const float*)d_in[0];   // source_feats (4096,1,4)
  const float* pos = (const float*)d_in[1];   // node_positions (4096,3)
  float* out = (float*)d_out;
  es_main<<<1024, 448, 0, stream>>>(sf, pos, out);
}

// Round 6
// 95.543 us; speedup vs baseline: 1.0200x; 1.0126x over previous
//
#include <hip/hip_runtime.h>
#include <math.h>

namespace {

constexpr int   MTOT   = 4096;       // total nodes
constexpr float H      = 0.1f;

// W_FACTORS = sqrt((0.5^2 + sigma^2)/2), sigma in {0.4, 0.8, 1.2, 1.6}
constexpr float W0 = 0.45276925690687087f;
constexpr float W1 = 0.66708320320631664f;
constexpr float W2 = 0.91923881554251174f;
constexpr float W3 = 1.18532695911296985f;

constexpr float KCOUL   = 14.399645478425669f;  // e*1e10/eps0/(4*pi)
constexpr float HALF_L1 = 2.8867513459481287f;  // 0.5*sqrt(3)/0.3
constexpr float SQRTPI  = 1.7724538509055159f;

// pk_r = 0.47047*(0.5/W_r) ;  c2_r = -(0.5/W_r)^2 * log2(e)
constexpr float PK0 = 0.5195472f, PK1 = 0.3526314f, PK2 = 0.2559019f, PK3 = 0.1984558f;
constexpr float C20 = -1.7593842f, C21 = -0.8105028f, C22 = -0.4268329f, C23 = -0.2567073f;
// A&S 7.1.25 coefficients (|err| <= 2.5e-5); a1+a2+a3 == 1 -> erf(0)=0
constexpr float EA1 = 0.3480242f, EA2 = -0.0958798f, EA3 = 0.7478556f;

// 1/(ds + 1e-6) for ds = h, h*sqrt2, 2h
constexpr float RCP_H   = 9.9999000f;
constexpr float RCP_HS2 = 7.0710178f;
constexpr float RCP_2H  = 4.9999750f;

__device__ __forceinline__ float fast_rcp(float x)  { return __builtin_amdgcn_rcpf(x); }
__device__ __forceinline__ float fast_rsq(float x)  { return __builtin_amdgcn_rsqf(x); }
__device__ __forceinline__ float fast_exp2(float x) { return __builtin_amdgcn_exp2f(x); }

// q(x) = erfc-part: (a1 t + a2 t^2 + a3 t^3) * e^{-(kd)^2}, t = 1/(1+p*k*d)
// (used only in the cheap epilogue)
__device__ __forceinline__ float erf_q(float d, float d2, float pk, float c2) {
  float t = fast_rcp(__builtin_fmaf(d, pk, 1.0f));
  float poly = t * __builtin_fmaf(t, __builtin_fmaf(t, EA3, EA2), EA1);
  return poly * fast_exp2(d2 * c2);
}

// project (7 x 4) site-features S[j*4+r] -> 16 outputs
__device__ __forceinline__ float project_one(const float* S, int k) {
  if (k < 4) return S[k];
  int q = k - 4;
  int r = q / 3;
  int comp = q - 3 * r;
  int j1, j2;
  if (comp == 0)      { j1 = 2; j2 = 5; }
  else if (comp == 1) { j1 = 3; j2 = 6; }
  else                { j1 = 1; j2 = 4; }
  return HALF_L1 * (S[j1 * 4 + r] - S[j2 * 4 + r]);
}

// grid: 256 blocks = 32 graphs x 8 node-blocks; block: 896 thr = 112 sites x 8 chunks
// (best-measured structure: minimal staging redundancy; kernel is trans-pipe bound,
//  extra occupancy measured neutral-to-negative in R4/R5)
__global__ __launch_bounds__(896, 4) void es_main(
    const float* __restrict__ sf,   // (4096, 4)
    const float* __restrict__ pos,  // (4096, 3)
    float* __restrict__ out)        // [0:65536) features, [65536:131072) self_terms
{
  __shared__ float4 s_site[896];      // whole graph's sites: xyz + charge
  __shared__ float4 s_part[8 * 112];  // per-chunk partial (a0..a3) per site
  __shared__ float  s_feat[112 * 4];  // per-site features
  __shared__ float  s_self[112 * 4];  // per-site self term

  const int b   = blockIdx.x;
  const int g   = b >> 3;    // graph
  const int nb  = b & 7;     // node-block: nodes [nb*16, nb*16+16) of graph
  const int tid = threadIdx.x;

  // ---- stage all 896 sites of this graph ----
  {
    const int s  = tid;
    const int i  = (s * 9363) >> 16;   // s/7 (exact for s < 896)
    const int bb = s - i * 7;
    const int node = g * 128 + i;
    float px = pos[node * 3 + 0];
    float py = pos[node * 3 + 1];
    float pz = pos[node * 3 + 2];
    float ch;
    if (bb == 0) {
      ch = sf[node * 4 + 0];
    } else {
      int ax = (bb - 1) % 3;                 // 0:x 1:y 2:z
      int comp = (ax == 0) ? 3 : ax;         // b1/b4 -> s3, b2/b5 -> s1, b3/b6 -> s2
      float sgn = (bb >= 4) ? -5.0f : 5.0f;  // 1/(2h), negated for back offsets
      ch = sf[node * 4 + comp] * sgn;
      float o = (bb >= 4) ? -H : H;
      if (ax == 0)      px += o;
      else if (ax == 1) py += o;
      else              pz += o;
    }
    s_site[s] = make_float4(px, py, pz, ch);
  }
  __syncthreads();

  // ---- main pair loop: thread = (target site, source chunk) ----
  const int site_local = tid % 112;
  const int chunk      = tid / 112;
  const int sl         = nb * 112 + site_local;   // target site within graph
  const float4 t4 = s_site[sl];
  const int src_base  = chunk * 112;
  const int cmp_local = sl - src_base;  // own-site index within this chunk (may be OOR)

  float S = 0.f, q0 = 0.f, q1 = 0.f, q2 = 0.f, q3 = 0.f;
  for (int it0 = 0; it0 < 112; it0 += 14) {
    const int tgt = cmp_local - it0;
#pragma unroll
    for (int u = 0; u < 14; ++u) {
      float4 s4 = s_site[src_base + it0 + u];  // <=2 distinct addrs per wave: broadcast
      float dx = t4.x - s4.x;
      float dy = t4.y - s4.y;
      float dz = t4.z - s4.z;
      float d2 = __builtin_fmaf(dx, dx, 1e-12f);
      d2 = __builtin_fmaf(dy, dy, d2);
      d2 = __builtin_fmaf(dz, dz, d2);
      float rd = fast_rsq(d2);
      float d  = d2 * rd;
      float cv = (u == tgt) ? 0.0f : s4.w * rd;  // mask only the singular own-site pair
      S += cv;
      // t_r = 1/(1 + pk_r * d) for all four radials via ONE rcp (batch inversion)
      float u0 = __builtin_fmaf(d, PK0, 1.0f);
      float u1 = __builtin_fmaf(d, PK1, 1.0f);
      float u2 = __builtin_fmaf(d, PK2, 1.0f);
      float u3 = __builtin_fmaf(d, PK3, 1.0f);
      float m01   = u0 * u1;
      float m012  = m01 * u2;
      float m0123 = m012 * u3;
      float inv   = fast_rcp(m0123);   // 1/(u0 u1 u2 u3)
      float i012  = inv * u3;          // 1/(u0 u1 u2)
      float i01   = i012 * u2;         // 1/(u0 u1)
      float t3v = inv  * m012;
      float t2v = i012 * m01;
      float t1v = i01  * u0;
      float t0v = i01  * u1;
      float p0 = t0v * __builtin_fmaf(t0v, __builtin_fmaf(t0v, EA3, EA2), EA1);
      float p1 = t1v * __builtin_fmaf(t1v, __builtin_fmaf(t1v, EA3, EA2), EA1);
      float p2 = t2v * __builtin_fmaf(t2v, __builtin_fmaf(t2v, EA3, EA2), EA1);
      float p3 = t3v * __builtin_fmaf(t3v, __builtin_fmaf(t3v, EA3, EA2), EA1);
      q0 = __builtin_fmaf(cv * p0, fast_exp2(d2 * C20), q0);
      q1 = __builtin_fmaf(cv * p1, fast_exp2(d2 * C21), q1);
      q2 = __builtin_fmaf(cv * p2, fast_exp2(d2 * C22), q2);
      q3 = __builtin_fmaf(cv * p3, fast_exp2(d2 * C23), q3);
    }
  }
  s_part[chunk * 112 + site_local] = make_float4(S - q0, S - q1, S - q2, S - q3);
  __syncthreads();

  // ---- reduce chunks + self term + own-node correction (cancels to +c_a*diag) ----
  if (tid < 448) {
    const int site = tid >> 2;   // 0..111
    const int r    = tid & 3;
    const float* pf = (const float*)s_part;
    float tot = 0.f;
#pragma unroll
    for (int c = 0; c < 8; ++c) tot += pf[c * 448 + tid];

    const float w  = (r == 0) ? W0  : (r == 1) ? W1  : (r == 2) ? W2  : W3;
    const float pk = (r == 0) ? PK0 : (r == 1) ? PK1 : (r == 2) ? PK2 : PK3;
    const float c2 = (r == 0) ? C20 : (r == 1) ? C21 : (r == 2) ? C22 : C23;
    const float diag = fast_rcp(w * SQRTPI);
    const float ph1 = (1.f - erf_q(0.1f,        0.01f, pk, c2)) * RCP_H;
    const float ph2 = (1.f - erf_q(0.14142136f, 0.02f, pk, c2)) * RCP_HS2;
    const float ph3 = (1.f - erf_q(0.2f,        0.04f, pk, c2)) * RCP_2H;

    const int jn = (site * 9363) >> 16;  // node within block's 16 nodes
    const int ba = site - jn * 7;        // this site's offset index
    const int cbase = nb * 112 + jn * 7; // node's 7 sites in s_site
    float selfSum = 0.f, ca = 0.f;
#pragma unroll
    for (int i = 0; i < 7; ++i) {
      float ci = s_site[cbase + i].w;
      float ph;
      if (i == ba)                             ph = diag;
      else if (i == 0 || ba == 0)              ph = ph1;
      else if ((i - ba == 3) || (ba - i == 3)) ph = ph3;
      else                                     ph = ph2;
      selfSum = __builtin_fmaf(ci, ph, selfSum);
      if (i == ba) ca = ci;
    }
    // features(site) = K*(tot - ownNodeOffDiag) + K*selfSum = K*(tot + c_a*diag)
    s_self[tid] = KCOUL * selfSum;
    s_feat[tid] = KCOUL * __builtin_fmaf(ca, diag, tot);
  }
  __syncthreads();

  // ---- projection + coalesced write (16 nodes x 16 outputs) ----
  if (tid < 256) {
    const int node = tid >> 4;
    const int k    = tid & 15;
    const int m    = g * 128 + nb * 16 + node;
    float vf = project_one(&s_feat[node * 28], k);
    float vs = project_one(&s_self[node * 28], k);
    out[m * 16 + k]             = vf;
    out[MTOT * 16 + m * 16 + k] = vs;
  }
}

} // namespace

extern "C" void kernel_launch(void* const* d_in, const int* in_sizes, int n_in,
                              void* d_out, int out_size, void* d_ws, size_t ws_size,
                              hipStream_t stream) {
  const float* sf  = (const float*)d_in[0];   // source_feats (4096,1,4)
  const float* pos = (const float*)d_in[1];   // node_positions (4096,3)
  float* out = (float*)d_out;
  es_main<<<256, 896, 0, stream>>>(sf, pos, out);
}

// Round 7
// 94.538 us; speedup vs baseline: 1.0309x; 1.0106x over previous
//
#include <hip/hip_runtime.h>
#include <math.h>

namespace {

constexpr int   MTOT   = 4096;       // total nodes
constexpr float H      = 0.1f;

// W_FACTORS = sqrt((0.5^2 + sigma^2)/2), sigma in {0.4, 0.8, 1.2, 1.6}
constexpr float W0 = 0.45276925690687087f;
constexpr float W1 = 0.66708320320631664f;
constexpr float W2 = 0.91923881554251174f;
constexpr float W3 = 1.18532695911296985f;

constexpr float KCOUL   = 14.399645478425669f;  // e*1e10/eps0/(4*pi)
constexpr float HALF_L1 = 2.8867513459481287f;  // 0.5*sqrt(3)/0.3
constexpr float SQRTPI  = 1.7724538509055159f;

// pk_r = 0.47047*(0.5/W_r) ;  c2_r = -(0.5/W_r)^2 * log2(e)
constexpr float PK0 = 0.5195472f, PK1 = 0.3526314f, PK2 = 0.2559019f, PK3 = 0.1984558f;
constexpr float C20 = -1.7593842f, C21 = -0.8105028f, C22 = -0.4268329f, C23 = -0.2567073f;
// A&S 7.1.25 coefficients (|err| <= 2.5e-5); a1+a2+a3 == 1 -> erf(0)=0
constexpr float EA1 = 0.3480242f, EA2 = -0.0958798f, EA3 = 0.7478556f;

// 1/(ds + 1e-6) for ds = h, h*sqrt2, 2h
constexpr float RCP_H   = 9.9999000f;
constexpr float RCP_HS2 = 7.0710178f;
constexpr float RCP_2H  = 4.9999750f;

__device__ __forceinline__ float fast_rcp(float x)  { return __builtin_amdgcn_rcpf(x); }
__device__ __forceinline__ float fast_rsq(float x)  { return __builtin_amdgcn_rsqf(x); }
__device__ __forceinline__ float fast_exp2(float x) { return __builtin_amdgcn_exp2f(x); }

// q(x) = erfc-part: (a1 t + a2 t^2 + a3 t^3) * e^{-(kd)^2}, t = 1/(1+p*k*d)
__device__ __forceinline__ float erf_q(float d, float d2, float pk, float c2) {
  float t = fast_rcp(__builtin_fmaf(d, pk, 1.0f));
  float poly = t * __builtin_fmaf(t, __builtin_fmaf(t, EA3, EA2), EA1);
  return poly * fast_exp2(d2 * c2);
}

// project (7 x 4) site-features S[j*4+r] -> 16 outputs
__device__ __forceinline__ float project_one(const float* S, int k) {
  if (k < 4) return S[k];
  int q = k - 4;
  int r = q / 3;
  int comp = q - 3 * r;
  int j1, j2;
  if (comp == 0)      { j1 = 2; j2 = 5; }
  else if (comp == 1) { j1 = 3; j2 = 6; }
  else                { j1 = 1; j2 = 4; }
  return HALF_L1 * (S[j1 * 4 + r] - S[j2 * 4 + r]);
}

// grid: 256 blocks = 32 graphs x 8 node-blocks; block: 896 thr = 112 sites x 8 chunks
// Double-buffered register prefetch of 7 sources/group hides ds_read latency.
__global__ __launch_bounds__(896, 4) void es_main(
    const float* __restrict__ sf,   // (4096, 4)
    const float* __restrict__ pos,  // (4096, 3)
    float* __restrict__ out)        // [0:65536) features, [65536:131072) self_terms
{
  __shared__ float4 s_site[896];      // whole graph's sites: xyz + charge
  __shared__ float4 s_part[8 * 112];  // per-chunk partial (a0..a3) per site
  __shared__ float  s_feat[112 * 4];  // per-site features
  __shared__ float  s_self[112 * 4];  // per-site self term

  const int b   = blockIdx.x;
  const int g   = b >> 3;    // graph
  const int nb  = b & 7;     // node-block: nodes [nb*16, nb*16+16) of graph
  const int tid = threadIdx.x;

  // ---- stage all 896 sites of this graph ----
  {
    const int s  = tid;
    const int i  = (s * 9363) >> 16;   // s/7 (exact for s < 896)
    const int bb = s - i * 7;
    const int node = g * 128 + i;
    float px = pos[node * 3 + 0];
    float py = pos[node * 3 + 1];
    float pz = pos[node * 3 + 2];
    float ch;
    if (bb == 0) {
      ch = sf[node * 4 + 0];
    } else {
      int ax = (bb - 1) % 3;                 // 0:x 1:y 2:z
      int comp = (ax == 0) ? 3 : ax;         // b1/b4 -> s3, b2/b5 -> s1, b3/b6 -> s2
      float sgn = (bb >= 4) ? -5.0f : 5.0f;  // 1/(2h), negated for back offsets
      ch = sf[node * 4 + comp] * sgn;
      float o = (bb >= 4) ? -H : H;
      if (ax == 0)      px += o;
      else if (ax == 1) py += o;
      else              pz += o;
    }
    s_site[s] = make_float4(px, py, pz, ch);
  }
  __syncthreads();

  // ---- main pair loop: thread = (target site, source chunk) ----
  const int site_local = tid % 112;
  const int chunk      = tid / 112;
  const int sl         = nb * 112 + site_local;   // target site within graph
  const float4 t4 = s_site[sl];
  const int src_base  = chunk * 112;
  const int cmp_local = sl - src_base;  // own-site index within this chunk (may be OOR)

  float S = 0.f, q0 = 0.f, q1 = 0.f, q2 = 0.f, q3 = 0.f;

  float4 bufA[7], bufB[7];

  auto load7 = [&](float4* buf, int it0) {
#pragma unroll
    for (int u = 0; u < 7; ++u) buf[u] = s_site[src_base + it0 + u];
  };
  auto comp7 = [&](const float4* buf, int it0) {
    const int tgt = cmp_local - it0;
#pragma unroll
    for (int u = 0; u < 7; ++u) {
      float4 s4 = buf[u];
      float dx = t4.x - s4.x;
      float dy = t4.y - s4.y;
      float dz = t4.z - s4.z;
      float d2 = __builtin_fmaf(dx, dx, 1e-12f);
      d2 = __builtin_fmaf(dy, dy, d2);
      d2 = __builtin_fmaf(dz, dz, d2);
      float rd = fast_rsq(d2);
      float d  = d2 * rd;
      float cv = (u == tgt) ? 0.0f : s4.w * rd;  // mask only the singular own-site pair
      S += cv;
      q0 = __builtin_fmaf(cv, erf_q(d, d2, PK0, C20), q0);
      q1 = __builtin_fmaf(cv, erf_q(d, d2, PK1, C21), q1);
      q2 = __builtin_fmaf(cv, erf_q(d, d2, PK2, C22), q2);
      q3 = __builtin_fmaf(cv, erf_q(d, d2, PK3, C23), q3);
    }
  };

  // 16 groups of 7, software-pipelined with two register buffers
  load7(bufA, 0);
  for (int gg = 0; gg < 8; ++gg) {
    const int base = gg * 14;
    load7(bufB, base + 7);
    comp7(bufA, base);
    if (gg < 7) load7(bufA, base + 14);
    comp7(bufB, base + 7);
  }

  s_part[chunk * 112 + site_local] = make_float4(S - q0, S - q1, S - q2, S - q3);
  __syncthreads();

  // ---- reduce chunks + self term + own-node correction (cancels to +c_a*diag) ----
  if (tid < 448) {
    const int site = tid >> 2;   // 0..111
    const int r    = tid & 3;
    const float* pf = (const float*)s_part;
    float tot = 0.f;
#pragma unroll
    for (int c = 0; c < 8; ++c) tot += pf[c * 448 + tid];

    const float w  = (r == 0) ? W0  : (r == 1) ? W1  : (r == 2) ? W2  : W3;
    const float pk = (r == 0) ? PK0 : (r == 1) ? PK1 : (r == 2) ? PK2 : PK3;
    const float c2 = (r == 0) ? C20 : (r == 1) ? C21 : (r == 2) ? C22 : C23;
    const float diag = fast_rcp(w * SQRTPI);
    const float ph1 = (1.f - erf_q(0.1f,        0.01f, pk, c2)) * RCP_H;
    const float ph2 = (1.f - erf_q(0.14142136f, 0.02f, pk, c2)) * RCP_HS2;
    const float ph3 = (1.f - erf_q(0.2f,        0.04f, pk, c2)) * RCP_2H;

    const int jn = (site * 9363) >> 16;  // node within block's 16 nodes
    const int ba = site - jn * 7;        // this site's offset index
    const int cbase = nb * 112 + jn * 7; // node's 7 sites in s_site
    float selfSum = 0.f, ca = 0.f;
#pragma unroll
    for (int i = 0; i < 7; ++i) {
      float ci = s_site[cbase + i].w;
      float ph;
      if (i == ba)                             ph = diag;
      else if (i == 0 || ba == 0)              ph = ph1;
      else if ((i - ba == 3) || (ba - i == 3)) ph = ph3;
      else                                     ph = ph2;
      selfSum = __builtin_fmaf(ci, ph, selfSum);
      if (i == ba) ca = ci;
    }
    // features(site) = K*(tot - ownNodeOffDiag) + K*selfSum = K*(tot + c_a*diag)
    s_self[tid] = KCOUL * selfSum;
    s_feat[tid] = KCOUL * __builtin_fmaf(ca, diag, tot);
  }
  __syncthreads();

  // ---- projection + coalesced write (16 nodes x 16 outputs) ----
  if (tid < 256) {
    const int node = tid >> 4;
    const int k    = tid & 15;
    const int m    = g * 128 + nb * 16 + node;
    float vf = project_one(&s_feat[node * 28], k);
    float vs = project_one(&s_self[node * 28], k);
    out[m * 16 + k]             = vf;
    out[MTOT * 16 + m * 16 + k] = vs;
  }
}

} // namespace

extern "C" void kernel_launch(void* const* d_in, const int* in_sizes, int n_in,
                              void* d_out, int out_size, void* d_ws, size_t ws_size,
                              hipStream_t stream) {
  const float* sf  = (const float*)d_in[0];   // source_feats (4096,1,4)
  const float* pos = (const float*)d_in[1];   // node_positions (4096,3)
  float* out = (float*)d_out;
  es_main<<<256, 896, 0, stream>>>(sf, pos, out);
}

// Round 10
// 91.733 us; speedup vs baseline: 1.0624x; 1.0306x over previous
//
#include <hip/hip_runtime.h>
#include <math.h>

namespace {

constexpr int   MTOT = 4096;       // total nodes
constexpr float H    = 0.1f;

// W_FACTORS = sqrt((0.5^2 + sigma^2)/2), sigma in {0.4, 0.8, 1.2, 1.6}
constexpr float W0 = 0.45276925690687087f;
constexpr float W1 = 0.66708320320631664f;
constexpr float W2 = 0.91923881554251174f;
constexpr float W3 = 1.18532695911296985f;

constexpr float KCOUL   = 14.399645478425669f;  // e*1e10/eps0/(4*pi)
constexpr float HALF_L1 = 2.8867513459481287f;  // 0.5*sqrt(3)/0.3
constexpr float SQRTPI  = 1.7724538509055159f;

// A&S 7.1.25 (|err| <= 2.5e-5, proven in R2-R7):
// erf(k d) = 1 - (a1 t + a2 t^2 + a3 t^3) * e^{-(kd)^2},  t = 1/(1 + p*k*d)
// pk_r = 0.47047*k_r ; c2_r = -k_r^2*log2(e) ; k_r = 0.5/W_r
constexpr float PK0 = 0.5195472f, PK1 = 0.3526314f, PK2 = 0.2559019f, PK3 = 0.1984558f;
constexpr float C20 = -1.7593842f, C21 = -0.8105028f, C22 = -0.4268329f, C23 = -0.2567073f;
constexpr float EA1 = 0.3480242f, EA2 = -0.0958798f, EA3 = 0.7478556f;
constexpr float RCP_H = 9.9999000f, RCP_HS2 = 7.0710178f, RCP_2H = 4.9999750f;

__device__ __forceinline__ float fast_rcp(float x)  { return __builtin_amdgcn_rcpf(x); }
__device__ __forceinline__ float fast_rsq(float x)  { return __builtin_amdgcn_rsqf(x); }
__device__ __forceinline__ float fast_exp2(float x) { return __builtin_amdgcn_exp2f(x); }

// q = erfc-part of A&S 7.1.25
__device__ __forceinline__ float erf_q(float d, float d2, float pk, float c2) {
  float t = fast_rcp(__builtin_fmaf(d, pk, 1.0f));
  float poly = t * __builtin_fmaf(t, __builtin_fmaf(t, EA3, EA2), EA1);
  return poly * fast_exp2(d2 * c2);
}

// project (7 x 4) site-features S[j*4+r] -> 16 outputs
__device__ __forceinline__ float project_one(const float* S, int k) {
  if (k < 4) return S[k];
  int q = k - 4;
  int r = q / 3;
  int comp = q - 3 * r;
  int j1, j2;
  if (comp == 0)      { j1 = 2; j2 = 5; }
  else if (comp == 1) { j1 = 3; j2 = 6; }
  else                { j1 = 1; j2 = 4; }
  return HALF_L1 * (S[j1 * 4 + r] - S[j2 * 4 + r]);
}

// grid: 256 blocks = 32 graphs x 8 node-blocks; block: 896 thr = 112 sites x 8 chunks.
// Sources processed NODE-wise: d^2 of a node's 7 sites from one (v, v2) via 1 fma each.
// d2 clamped: the fma-reformulated own-site pair can land at ~-2.6e-10 (cancellation).
__global__ __launch_bounds__(896, 4) void es_main(
    const float* __restrict__ sf,   // (4096, 4)
    const float* __restrict__ pos,  // (4096, 3)
    float* __restrict__ out)        // [0:65536) features, [65536:131072) self_terms
{
  __shared__ float4 s_pos4[128];      // node centers
  __shared__ float4 s_chg4[128];      // prescaled charges {s0, 5s3, 5s1, 5s2}
  __shared__ float4 s_part[8 * 112];  // per-chunk partial (a0..a3) per site
  __shared__ float  s_feat[448];
  __shared__ float  s_self[448];

  const int b   = blockIdx.x;
  const int g   = b >> 3;    // graph
  const int nb  = b & 7;     // node-block: nodes [nb*16, nb*16+16)
  const int tid = threadIdx.x;

  // ---- stage node centers + prescaled charges ----
  if (tid < 128) {
    const float* p = pos + (size_t)(g * 128 + tid) * 3;
    s_pos4[tid] = make_float4(p[0], p[1], p[2], 0.0f);
  } else if (tid < 256) {
    const int i = tid - 128;
    const float4 s = ((const float4*)sf)[g * 128 + i];
    s_chg4[i] = make_float4(s.x, 5.0f * s.w, 5.0f * s.y, 5.0f * s.z);
  }
  __syncthreads();

  // ---- per-thread target site ----
  const int site_local = tid % 112;
  const int chunk      = tid / 112;          // 0..7, 16 source nodes each
  const int sl   = nb * 112 + site_local;    // target site in graph [0,896)
  const int jown = (sl * 9363) >> 16;        // sl/7: own node [0,128)
  const int aoff = sl - jown * 7;            // own offset index 0..6

  const float4 cp = s_pos4[jown];
  const float tx = cp.x + ((aoff == 1) ? H : (aoff == 4) ? -H : 0.0f);
  const float ty = cp.y + ((aoff == 2) ? H : (aoff == 5) ? -H : 0.0f);
  const float tz = cp.z + ((aoff == 3) ? H : (aoff == 6) ? -H : 0.0f);

  float S = 0.f, q0 = 0.f, q1 = 0.f, q2 = 0.f, q3 = 0.f;

  auto acc = [&](float d2raw, float c) {
    float d2 = fmaxf(d2raw, 1e-12f);   // guard: fma cancellation can go slightly negative
    float rd = fast_rsq(d2);
    float d  = d2 * rd;
    float cv = c * rd;
    S += cv;
    q0 = __builtin_fmaf(cv, erf_q(d, d2, PK0, C20), q0);
    q1 = __builtin_fmaf(cv, erf_q(d, d2, PK1, C21), q1);
    q2 = __builtin_fmaf(cv, erf_q(d, d2, PK2, C22), q2);
    q3 = __builtin_fmaf(cv, erf_q(d, d2, PK3, C23), q3);
  };

  const int j0 = chunk * 16;
#pragma unroll 2
  for (int jj = 0; jj < 16; ++jj) {
    const int j = j0 + jj;
    const float4 p4 = s_pos4[j];   // <=2 distinct addrs per wave: broadcast
    const float4 c4 = s_chg4[j];
    const float vx = tx - p4.x;
    const float vy = ty - p4.y;
    const float vz = tz - p4.z;
    const float v2 = __builtin_fmaf(vx, vx, __builtin_fmaf(vy, vy, vz * vz));
    const float w2 = v2 + 0.01f;
    const bool own = (j == jown);
    // 7 site-pairs of this source node; mask only the singular own-site pair
    acc(v2,                            (own & (aoff == 0)) ? 0.0f :  c4.x);
    acc(__builtin_fmaf(vx, -0.2f, w2), (own & (aoff == 1)) ? 0.0f :  c4.y);
    acc(__builtin_fmaf(vy, -0.2f, w2), (own & (aoff == 2)) ? 0.0f :  c4.z);
    acc(__builtin_fmaf(vz, -0.2f, w2), (own & (aoff == 3)) ? 0.0f :  c4.w);
    acc(__builtin_fmaf(vx,  0.2f, w2), (own & (aoff == 4)) ? 0.0f : -c4.y);
    acc(__builtin_fmaf(vy,  0.2f, w2), (own & (aoff == 5)) ? 0.0f : -c4.z);
    acc(__builtin_fmaf(vz,  0.2f, w2), (own & (aoff == 6)) ? 0.0f : -c4.w);
  }

  s_part[chunk * 112 + site_local] = make_float4(S - q0, S - q1, S - q2, S - q3);
  __syncthreads();

  // ---- reduce chunks + self term + own-node correction (cancels to +c_a*diag) ----
  if (tid < 448) {
    const int site = tid >> 2;   // 0..111
    const int r    = tid & 3;
    const float* pf = (const float*)s_part;
    float tot = 0.f;
#pragma unroll
    for (int c = 0; c < 8; ++c) tot += pf[c * 448 + tid];

    const float w  = (r == 0) ? W0  : (r == 1) ? W1  : (r == 2) ? W2  : W3;
    const float pk = (r == 0) ? PK0 : (r == 1) ? PK1 : (r == 2) ? PK2 : PK3;
    const float c2 = (r == 0) ? C20 : (r == 1) ? C21 : (r == 2) ? C22 : C23;
    const float diag = fast_rcp(w * SQRTPI);
    const float ph1 = (1.f - erf_q(0.1f,        0.01f, pk, c2)) * RCP_H;
    const float ph2 = (1.f - erf_q(0.14142136f, 0.02f, pk, c2)) * RCP_HS2;
    const float ph3 = (1.f - erf_q(0.2f,        0.04f, pk, c2)) * RCP_2H;

    const int jn = (site * 9363) >> 16;  // node within block's 16 nodes
    const int ba = site - jn * 7;        // this site's offset index
    const float4 c4 = s_chg4[nb * 16 + jn];
    float selfSum = 0.f, ca = 0.f;
#pragma unroll
    for (int i = 0; i < 7; ++i) {
      const float ci = (i == 0) ?  c4.x : (i == 1) ?  c4.y : (i == 2) ?  c4.z :
                       (i == 3) ?  c4.w : (i == 4) ? -c4.y : (i == 5) ? -c4.z : -c4.w;
      float ph;
      if (i == ba)                             ph = diag;
      else if (i == 0 || ba == 0)              ph = ph1;
      else if ((i - ba == 3) || (ba - i == 3)) ph = ph3;
      else                                     ph = ph2;
      selfSum = __builtin_fmaf(ci, ph, selfSum);
      if (i == ba) ca = ci;
    }
    s_self[tid] = KCOUL * selfSum;
    s_feat[tid] = KCOUL * __builtin_fmaf(ca, diag, tot);
  }
  __syncthreads();

  // ---- projection + coalesced write (16 nodes x 16 outputs) ----
  if (tid < 256) {
    const int node = tid >> 4;
    const int k    = tid & 15;
    const int m    = g * 128 + nb * 16 + node;
    float vf = project_one(&s_feat[node * 28], k);
    float vs = project_one(&s_self[node * 28], k);
    out[m * 16 + k]             = vf;
    out[MTOT * 16 + m * 16 + k] = vs;
  }
}

} // namespace

extern "C" void kernel_launch(void* const* d_in, const int* in_sizes, int n_in,
                              void* d_out, int out_size, void* d_ws, size_t ws_size,
                              hipStream_t stream) {
  const float* sf  = (const float*)d_in[0];   // source_feats (4096,1,4)
  const float* pos = (const float*)d_in[1];   // node_positions (4096,3)
  float* out = (float*)d_out;
  es_main<<<256, 896, 0, stream>>>(sf, pos, out);
}

// Round 12
// 82.174 us; speedup vs baseline: 1.1860x; 1.1163x over previous
//
#include <hip/hip_runtime.h>
#include <math.h>

namespace {

constexpr int   MTOT = 4096;       // total nodes
constexpr float H    = 0.1f;

// W_FACTORS = sqrt((0.5^2 + sigma^2)/2), sigma in {0.4, 0.8, 1.2, 1.6}
constexpr float W0 = 0.45276925690687087f;
constexpr float W1 = 0.66708320320631664f;
constexpr float W2 = 0.91923881554251174f;
constexpr float W3 = 1.18532695911296985f;

constexpr float KCOUL   = 14.399645478425669f;  // e*1e10/eps0/(4*pi)
constexpr float HALF_L1 = 2.8867513459481287f;  // 0.5*sqrt(3)/0.3
constexpr float SQRTPI  = 1.7724538509055159f;

// k_r = 0.5/W_r
constexpr float K0 = 1.1043153f, K1 = 0.74953184f, K2 = 0.54392830f, K3 = 0.42182454f;

// epilogue erf (A&S 7.1.25, |err|<=2.5e-5): pk=0.47047*k, c2=-k^2*log2e
constexpr float PK0 = 0.5195472f, PK1 = 0.3526314f, PK2 = 0.2559019f, PK3 = 0.1984558f;
constexpr float C20 = -1.7593842f, C21 = -0.8105028f, C22 = -0.4268329f, C23 = -0.2567073f;
constexpr float EA1 = 0.3480242f, EA2 = -0.0958798f, EA3 = 0.7478556f;
constexpr float RCP_H = 9.9999000f, RCP_HS2 = 7.0710178f, RCP_2H = 4.9999750f;

// lookup table: 512 entries over d in [0, 7.68), h = 0.015
constexpr int   TABN  = 512;
constexpr float TAB_H = 0.015f;
constexpr float INV_H = 66.666664f;

__device__ __forceinline__ float fast_rcp(float x)  { return __builtin_amdgcn_rcpf(x); }
__device__ __forceinline__ float fast_rsq(float x)  { return __builtin_amdgcn_rsqf(x); }
__device__ __forceinline__ float fast_exp2(float x) { return __builtin_amdgcn_exp2f(x); }

// epilogue: q = erfc-part of A&S 7.1.25
__device__ __forceinline__ float erf_q(float d, float d2, float pk, float c2) {
  float t = fast_rcp(__builtin_fmaf(d, pk, 1.0f));
  float poly = t * __builtin_fmaf(t, __builtin_fmaf(t, EA3, EA2), EA1);
  return poly * fast_exp2(d2 * c2);
}

// project (7 x 4) site-features S[j*4+r] -> 16 outputs
__device__ __forceinline__ float project_one(const float* S, int k) {
  if (k < 4) return S[k];
  int q = k - 4;
  int r = q / 3;
  int comp = q - 3 * r;
  int j1, j2;
  if (comp == 0)      { j1 = 2; j2 = 5; }
  else if (comp == 1) { j1 = 3; j2 = 6; }
  else                { j1 = 1; j2 = 4; }
  return HALF_L1 * (S[j1 * 4 + r] - S[j2 * 4 + r]);
}

// grid: 256 blocks = 32 graphs x 8 node-blocks; block: 896 thr = 112 sites x 8 chunks.
// erf(k_r d) via per-block LDS table (value + PER-CELL slope, linear interp).
__global__ __launch_bounds__(896, 4) void es_main(
    const float* __restrict__ sf,   // (4096, 4)
    const float* __restrict__ pos,  // (4096, 3)
    float* __restrict__ out)        // [0:65536) features, [65536:131072) self_terms
{
  __shared__ float4 s_pos4[128];        // node centers
  __shared__ float4 s_chg4[128];        // prescaled charges {s0, 5s3, 5s1, 5s2}
  __shared__ float2 s_tab[4][TABN];     // (erf value, per-cell delta) per radial
  __shared__ float  s_tmp[4][TABN + 1]; // raw erf values for slope build
  __shared__ float4 s_part[8 * 112];    // per-chunk partial (a0..a3) per site
  __shared__ float  s_feat[448];
  __shared__ float  s_self[448];

  const int b   = blockIdx.x;
  const int g   = b >> 3;    // graph
  const int nb  = b & 7;     // node-block: nodes [nb*16, nb*16+16)
  const int tid = threadIdx.x;

  // ---- stage node centers + prescaled charges ----
  if (tid < 128) {
    const float* p = pos + (size_t)(g * 128 + tid) * 3;
    s_pos4[tid] = make_float4(p[0], p[1], p[2], 0.0f);
  } else if (tid < 256) {
    const int i = tid - 128;
    const float4 s = ((const float4*)sf)[g * 128 + i];
    s_chg4[i] = make_float4(s.x, 5.0f * s.w, 5.0f * s.y, 5.0f * s.z);
  }
  // ---- build erf tables with ACCURATE erff (one-time, ~4 erff/thread) ----
  if (tid <= TABN) {
    const float d = tid * TAB_H;
    s_tmp[0][tid] = erff(K0 * d);
    s_tmp[1][tid] = erff(K1 * d);
    s_tmp[2][tid] = erff(K2 * d);
    s_tmp[3][tid] = erff(K3 * d);
  }
  __syncthreads();
  if (tid < TABN) {
#pragma unroll
    for (int r = 0; r < 4; ++r) {
      const float v = s_tmp[r][tid];
      // slope in PER-CELL units: interp is v + delta * f with f in [0,1)
      s_tab[r][tid] = make_float2(v, s_tmp[r][tid + 1] - v);
    }
  }
  __syncthreads();

  // ---- per-thread target site ----
  const int site_local = tid % 112;
  const int chunk      = tid / 112;          // 0..7, 16 source nodes each
  const int sl   = nb * 112 + site_local;    // target site in graph [0,896)
  const int jown = (sl * 9363) >> 16;        // sl/7: own node [0,128)
  const int aoff = sl - jown * 7;            // own offset index 0..6

  const float4 cp = s_pos4[jown];
  const float tx = cp.x + ((aoff == 1) ? H : (aoff == 4) ? -H : 0.0f);
  const float ty = cp.y + ((aoff == 2) ? H : (aoff == 5) ? -H : 0.0f);
  const float tz = cp.z + ((aoff == 3) ? H : (aoff == 6) ? -H : 0.0f);

  float a0 = 0.f, a1 = 0.f, a2 = 0.f, a3 = 0.f;

  auto acc = [&](float d2raw, float c) {
    float d2 = fmaxf(d2raw, 1e-12f);   // guard: fma cancellation can go slightly negative
    float rd = fast_rsq(d2);
    float cv = c * rd;                 // charge / d
    float t  = (d2 * rd) * INV_H;      // d / h
    int  idx = (int)t;                 // trunc (t >= 0)
    float f  = t - (float)idx;         // frac in [0,1)
    idx = (idx < TABN - 1) ? idx : (TABN - 1);
    const float2 e0 = s_tab[0][idx];
    const float2 e1 = s_tab[1][idx];
    const float2 e2 = s_tab[2][idx];
    const float2 e3 = s_tab[3][idx];
    a0 = __builtin_fmaf(cv, __builtin_fmaf(e0.y, f, e0.x), a0);
    a1 = __builtin_fmaf(cv, __builtin_fmaf(e1.y, f, e1.x), a1);
    a2 = __builtin_fmaf(cv, __builtin_fmaf(e2.y, f, e2.x), a2);
    a3 = __builtin_fmaf(cv, __builtin_fmaf(e3.y, f, e3.x), a3);
  };

  const int j0 = chunk * 16;
#pragma unroll 2
  for (int jj = 0; jj < 16; ++jj) {
    const int j = j0 + jj;
    const float4 p4 = s_pos4[j];   // wave-uniform source node: broadcast
    const float4 c4 = s_chg4[j];
    const float vx = tx - p4.x;
    const float vy = ty - p4.y;
    const float vz = tz - p4.z;
    const float v2 = __builtin_fmaf(vx, vx, __builtin_fmaf(vy, vy, vz * vz));
    const float w2 = v2 + 0.01f;
    const bool own = (j == jown);
    // 7 site-pairs of this source node; mask only the singular own-site pair
    acc(v2,                            (own & (aoff == 0)) ? 0.0f :  c4.x);
    acc(__builtin_fmaf(vx, -0.2f, w2), (own & (aoff == 1)) ? 0.0f :  c4.y);
    acc(__builtin_fmaf(vy, -0.2f, w2), (own & (aoff == 2)) ? 0.0f :  c4.z);
    acc(__builtin_fmaf(vz, -0.2f, w2), (own & (aoff == 3)) ? 0.0f :  c4.w);
    acc(__builtin_fmaf(vx,  0.2f, w2), (own & (aoff == 4)) ? 0.0f : -c4.y);
    acc(__builtin_fmaf(vy,  0.2f, w2), (own & (aoff == 5)) ? 0.0f : -c4.z);
    acc(__builtin_fmaf(vz,  0.2f, w2), (own & (aoff == 6)) ? 0.0f : -c4.w);
  }

  s_part[chunk * 112 + site_local] = make_float4(a0, a1, a2, a3);
  __syncthreads();

  // ---- reduce chunks + self term + own-node correction (cancels to +c_a*diag) ----
  if (tid < 448) {
    const int site = tid >> 2;   // 0..111
    const int r    = tid & 3;
    const float* pf = (const float*)s_part;
    float tot = 0.f;
#pragma unroll
    for (int c = 0; c < 8; ++c) tot += pf[c * 448 + tid];

    const float w  = (r == 0) ? W0  : (r == 1) ? W1  : (r == 2) ? W2  : W3;
    const float pk = (r == 0) ? PK0 : (r == 1) ? PK1 : (r == 2) ? PK2 : PK3;
    const float c2 = (r == 0) ? C20 : (r == 1) ? C21 : (r == 2) ? C22 : C23;
    const float diag = fast_rcp(w * SQRTPI);
    const float ph1 = (1.f - erf_q(0.1f,        0.01f, pk, c2)) * RCP_H;
    const float ph2 = (1.f - erf_q(0.14142136f, 0.02f, pk, c2)) * RCP_HS2;
    const float ph3 = (1.f - erf_q(0.2f,        0.04f, pk, c2)) * RCP_2H;

    const int jn = (site * 9363) >> 16;  // node within block's 16 nodes
    const int ba = site - jn * 7;        // this site's offset index
    const float4 c4 = s_chg4[nb * 16 + jn];
    float selfSum = 0.f, ca = 0.f;
#pragma unroll
    for (int i = 0; i < 7; ++i) {
      const float ci = (i == 0) ?  c4.x : (i == 1) ?  c4.y : (i == 2) ?  c4.z :
                       (i == 3) ?  c4.w : (i == 4) ? -c4.y : (i == 5) ? -c4.z : -c4.w;
      float ph;
      if (i == ba)                             ph = diag;
      else if (i == 0 || ba == 0)              ph = ph1;
      else if ((i - ba == 3) || (ba - i == 3)) ph = ph3;
      else                                     ph = ph2;
      selfSum = __builtin_fmaf(ci, ph, selfSum);
      if (i == ba) ca = ci;
    }
    s_self[tid] = KCOUL * selfSum;
    s_feat[tid] = KCOUL * __builtin_fmaf(ca, diag, tot);
  }
  __syncthreads();

  // ---- projection + coalesced write (16 nodes x 16 outputs) ----
  if (tid < 256) {
    const int node = tid >> 4;
    const int k    = tid & 15;
    const int m    = g * 128 + nb * 16 + node;
    float vf = project_one(&s_feat[node * 28], k);
    float vs = project_one(&s_self[node * 28], k);
    out[m * 16 + k]             = vf;
    out[MTOT * 16 + m * 16 + k] = vs;
  }
}

} // namespace

extern "C" void kernel_launch(void* const* d_in, const int* in_sizes, int n_in,
                              void* d_out, int out_size, void* d_ws, size_t ws_size,
                              hipStream_t stream) {
  const float* sf  = (const float*)d_in[0];   // source_feats (4096,1,4)
  const float* pos = (const float*)d_in[1];   // node_positions (4096,3)
  float* out = (float*)d_out;
  es_main<<<256, 896, 0, stream>>>(sf, pos, out);
}

// Round 13
// 75.206 us; speedup vs baseline: 1.2958x; 1.0927x over previous
//
#include <hip/hip_runtime.h>
#include <math.h>

namespace {

constexpr int   MTOT = 4096;       // total nodes
constexpr float H    = 0.1f;

// W_FACTORS = sqrt((0.5^2 + sigma^2)/2), sigma in {0.4, 0.8, 1.2, 1.6}
constexpr float W0 = 0.45276925690687087f;
constexpr float W1 = 0.66708320320631664f;
constexpr float W2 = 0.91923881554251174f;
constexpr float W3 = 1.18532695911296985f;

constexpr float KCOUL   = 14.399645478425669f;  // e*1e10/eps0/(4*pi)
constexpr float HALF_L1 = 2.8867513459481287f;  // 0.5*sqrt(3)/0.3
constexpr float SQRTPI  = 1.7724538509055159f;

// k_r = 0.5/W_r
constexpr float K0 = 1.1043153f, K1 = 0.74953184f, K2 = 0.54392830f, K3 = 0.42182454f;

// epilogue erf (A&S 7.1.25, |err|<=2.5e-5): pk=0.47047*k, c2=-k^2*log2e
constexpr float PK0 = 0.5195472f, PK1 = 0.3526314f, PK2 = 0.2559019f, PK3 = 0.1984558f;
constexpr float C20 = -1.7593842f, C21 = -0.8105028f, C22 = -0.4268329f, C23 = -0.2567073f;
constexpr float EA1 = 0.3480242f, EA2 = -0.0958798f, EA3 = 0.7478556f;
constexpr float RCP_H = 9.9999000f, RCP_HS2 = 7.0710178f, RCP_2H = 4.9999750f;

// lookup table: 512 entries over d in [0, 7.68), h = 0.015
constexpr int   TABN  = 512;
constexpr float TAB_H = 0.015f;
constexpr float INV_H = 66.666664f;

// saturation: all four erf(k_r d) == 1 to 5e-5 for d >= 2.88/k3 = 6.83.
// center-distance test with 0.2 site-offset margin: d_c^2 >= (7.03)^2
constexpr float SAT2 = 49.4f;

__device__ __forceinline__ float fast_rcp(float x)  { return __builtin_amdgcn_rcpf(x); }
__device__ __forceinline__ float fast_rsq(float x)  { return __builtin_amdgcn_rsqf(x); }
__device__ __forceinline__ float fast_exp2(float x) { return __builtin_amdgcn_exp2f(x); }

// epilogue: q = erfc-part of A&S 7.1.25
__device__ __forceinline__ float erf_q(float d, float d2, float pk, float c2) {
  float t = fast_rcp(__builtin_fmaf(d, pk, 1.0f));
  float poly = t * __builtin_fmaf(t, __builtin_fmaf(t, EA3, EA2), EA1);
  return poly * fast_exp2(d2 * c2);
}

// project (7 x 4) site-features S[j*4+r] -> 16 outputs
__device__ __forceinline__ float project_one(const float* S, int k) {
  if (k < 4) return S[k];
  int q = k - 4;
  int r = q / 3;
  int comp = q - 3 * r;
  int j1, j2;
  if (comp == 0)      { j1 = 2; j2 = 5; }
  else if (comp == 1) { j1 = 3; j2 = 6; }
  else                { j1 = 1; j2 = 4; }
  return HALF_L1 * (S[j1 * 4 + r] - S[j2 * 4 + r]);
}

__device__ __forceinline__ unsigned spread3(int v) {
  return (unsigned)((v & 1) | ((v & 2) << 2) | ((v & 4) << 4));
}

// grid: 256 blocks = 32 graphs x 8 node-blocks; block: 896 thr = 112 sites x 8 chunks.
// Nodes Morton-sorted per graph so consecutive nodes are spatially close ->
// wave-coherent saturation skip (erf==1 for all radials when d>6.8).
__global__ __launch_bounds__(896, 4) void es_main(
    const float* __restrict__ sf,   // (4096, 4)
    const float* __restrict__ pos,  // (4096, 3)
    float* __restrict__ out)        // [0:65536) features, [65536:131072) self_terms
{
  __shared__ float4   s_pos4[128];        // node centers (SORTED order)
  __shared__ float4   s_chg4[128];        // prescaled charges {s0,5s3,5s1,5s2} (SORTED)
  __shared__ int      s_orig[128];        // sorted slot -> original node index
  __shared__ unsigned s_key[128];         // morton<<7 | idx
  __shared__ float4   s_tabV[TABN];       // erf values  (r0..r3)
  __shared__ float4   s_tabD[TABN];       // per-cell deltas (r0..r3)
  __shared__ float    s_tmp[4][TABN + 1]; // raw erf values for build
  __shared__ float4   s_part[8 * 112];    // per-chunk partial (a0..a3) per site
  __shared__ float    s_feat[448];
  __shared__ float    s_self[448];

  const int b   = blockIdx.x;
  const int g   = b >> 3;    // graph
  const int nb  = b & 7;     // node-block (in sorted space)
  const int tid = threadIdx.x;

  // ---- load node data + morton key; build raw erf table ----
  float px = 0.f, py = 0.f, pz = 0.f;
  float4 myc = make_float4(0.f, 0.f, 0.f, 0.f);
  if (tid < 128) {
    const float* p = pos + (size_t)(g * 128 + tid) * 3;
    px = p[0]; py = p[1]; pz = p[2];
    const float4 s = ((const float4*)sf)[g * 128 + tid];
    myc = make_float4(s.x, 5.0f * s.w, 5.0f * s.y, 5.0f * s.z);
    int cx = (int)((px + 16.0f) * 0.25f); cx = (cx < 0) ? 0 : (cx > 7 ? 7 : cx);
    int cy = (int)((py + 16.0f) * 0.25f); cy = (cy < 0) ? 0 : (cy > 7 ? 7 : cy);
    int cz = (int)((pz + 16.0f) * 0.25f); cz = (cz < 0) ? 0 : (cz > 7 ? 7 : cz);
    unsigned mort = spread3(cx) | (spread3(cy) << 1) | (spread3(cz) << 2);
    s_key[tid] = (mort << 7) | (unsigned)tid;
  }
  if (tid <= TABN) {
    const float d = tid * TAB_H;
    s_tmp[0][tid] = erff(K0 * d);
    s_tmp[1][tid] = erff(K1 * d);
    s_tmp[2][tid] = erff(K2 * d);
    s_tmp[3][tid] = erff(K3 * d);
  }
  __syncthreads();

  // ---- rank-sort (broadcast loop) + scatter to sorted arrays; pack tables ----
  if (tid < 128) {
    const unsigned mykey = s_key[tid];
    int rank = 0;
    for (int t = 0; t < 128; ++t) rank += (s_key[t] < mykey) ? 1 : 0;
    s_pos4[rank] = make_float4(px, py, pz, 0.0f);
    s_chg4[rank] = myc;
    s_orig[rank] = tid;
  }
  if (tid < TABN) {
    const float v0 = s_tmp[0][tid], v1 = s_tmp[1][tid];
    const float v2v = s_tmp[2][tid], v3 = s_tmp[3][tid];
    s_tabV[tid] = make_float4(v0, v1, v2v, v3);
    s_tabD[tid] = make_float4(s_tmp[0][tid + 1] - v0, s_tmp[1][tid + 1] - v1,
                              s_tmp[2][tid + 1] - v2v, s_tmp[3][tid + 1] - v3);
  }
  __syncthreads();

  // ---- per-thread target site (sorted space) ----
  const int site_local = tid % 112;
  const int chunk      = tid / 112;          // 0..7, 16 source nodes each
  const int sl   = nb * 112 + site_local;    // target site in graph [0,896), sorted
  const int jown = (sl * 9363) >> 16;        // sl/7: own node slot [0,128)
  const int aoff = sl - jown * 7;            // own offset index 0..6

  const float4 cp = s_pos4[jown];
  const float tx = cp.x + ((aoff == 1) ? H : (aoff == 4) ? -H : 0.0f);
  const float ty = cp.y + ((aoff == 2) ? H : (aoff == 5) ? -H : 0.0f);
  const float tz = cp.z + ((aoff == 3) ? H : (aoff == 6) ? -H : 0.0f);

  float a0 = 0.f, a1 = 0.f, a2 = 0.f, a3 = 0.f, Ssat = 0.f;

  auto acc_full = [&](float d2raw, float c) {
    float d2 = fmaxf(d2raw, 1e-12f);   // guard: fma cancellation can go slightly negative
    float rd = fast_rsq(d2);
    float cv = c * rd;                 // charge / d
    float t  = (d2 * rd) * INV_H;      // d / h
    int  idx = (int)t;
    float f  = t - (float)idx;
    idx = (idx < TABN - 1) ? idx : (TABN - 1);
    f = fminf(f, 1.0f);                // no extrapolation beyond table end
    const float4 V = s_tabV[idx];
    const float4 D = s_tabD[idx];
    a0 = __builtin_fmaf(cv, __builtin_fmaf(D.x, f, V.x), a0);
    a1 = __builtin_fmaf(cv, __builtin_fmaf(D.y, f, V.y), a1);
    a2 = __builtin_fmaf(cv, __builtin_fmaf(D.z, f, V.z), a2);
    a3 = __builtin_fmaf(cv, __builtin_fmaf(D.w, f, V.w), a3);
  };

  const int j0 = chunk * 16;
  for (int jj = 0; jj < 16; ++jj) {
    const int j = j0 + jj;
    const float4 p4 = s_pos4[j];   // wave-(near-)uniform source node: broadcast
    const float4 c4 = s_chg4[j];
    const float vx = tx - p4.x;
    const float vy = ty - p4.y;
    const float vz = tz - p4.z;
    const float v2 = __builtin_fmaf(vx, vx, __builtin_fmaf(vy, vy, vz * vz));
    if (__any(v2 < SAT2)) {
      // full path (table lookups; far lanes read the saturated table end: correct)
      const float w2 = v2 + 0.01f;
      const bool own = (j == jown);
      acc_full(v2,                            (own & (aoff == 0)) ? 0.0f :  c4.x);
      acc_full(__builtin_fmaf(vx, -0.2f, w2), (own & (aoff == 1)) ? 0.0f :  c4.y);
      acc_full(__builtin_fmaf(vy, -0.2f, w2), (own & (aoff == 2)) ? 0.0f :  c4.z);
      acc_full(__builtin_fmaf(vz, -0.2f, w2), (own & (aoff == 3)) ? 0.0f :  c4.w);
      acc_full(__builtin_fmaf(vx,  0.2f, w2), (own & (aoff == 4)) ? 0.0f : -c4.y);
      acc_full(__builtin_fmaf(vy,  0.2f, w2), (own & (aoff == 5)) ? 0.0f : -c4.z);
      acc_full(__builtin_fmaf(vz,  0.2f, w2), (own & (aoff == 6)) ? 0.0f : -c4.w);
    } else {
      // saturated: all four erf == 1 -> contribution is just charge/d
      const float w2 = v2 + 0.01f;
      Ssat += c4.x * fast_rsq(v2);
      Ssat = __builtin_fmaf( c4.y, fast_rsq(__builtin_fmaf(vx, -0.2f, w2)), Ssat);
      Ssat = __builtin_fmaf( c4.z, fast_rsq(__builtin_fmaf(vy, -0.2f, w2)), Ssat);
      Ssat = __builtin_fmaf( c4.w, fast_rsq(__builtin_fmaf(vz, -0.2f, w2)), Ssat);
      Ssat = __builtin_fmaf(-c4.y, fast_rsq(__builtin_fmaf(vx,  0.2f, w2)), Ssat);
      Ssat = __builtin_fmaf(-c4.z, fast_rsq(__builtin_fmaf(vy,  0.2f, w2)), Ssat);
      Ssat = __builtin_fmaf(-c4.w, fast_rsq(__builtin_fmaf(vz,  0.2f, w2)), Ssat);
    }
  }
  a0 += Ssat; a1 += Ssat; a2 += Ssat; a3 += Ssat;

  s_part[chunk * 112 + site_local] = make_float4(a0, a1, a2, a3);
  __syncthreads();

  // ---- reduce chunks + self term + own-node correction (cancels to +c_a*diag) ----
  if (tid < 448) {
    const int site = tid >> 2;   // 0..111 (sorted space)
    const int r    = tid & 3;
    const float* pf = (const float*)s_part;
    float tot = 0.f;
#pragma unroll
    for (int c = 0; c < 8; ++c) tot += pf[c * 448 + tid];

    const float w  = (r == 0) ? W0  : (r == 1) ? W1  : (r == 2) ? W2  : W3;
    const float pk = (r == 0) ? PK0 : (r == 1) ? PK1 : (r == 2) ? PK2 : PK3;
    const float c2 = (r == 0) ? C20 : (r == 1) ? C21 : (r == 2) ? C22 : C23;
    const float diag = fast_rcp(w * SQRTPI);
    const float ph1 = (1.f - erf_q(0.1f,        0.01f, pk, c2)) * RCP_H;
    const float ph2 = (1.f - erf_q(0.14142136f, 0.02f, pk, c2)) * RCP_HS2;
    const float ph3 = (1.f - erf_q(0.2f,        0.04f, pk, c2)) * RCP_2H;

    const int jn = (site * 9363) >> 16;  // node within block's 16 (sorted space)
    const int ba = site - jn * 7;        // this site's offset index
    const float4 c4 = s_chg4[nb * 16 + jn];
    float selfSum = 0.f, ca = 0.f;
#pragma unroll
    for (int i = 0; i < 7; ++i) {
      const float ci = (i == 0) ?  c4.x : (i == 1) ?  c4.y : (i == 2) ?  c4.z :
                       (i == 3) ?  c4.w : (i == 4) ? -c4.y : (i == 5) ? -c4.z : -c4.w;
      float ph;
      if (i == ba)                             ph = diag;
      else if (i == 0 || ba == 0)              ph = ph1;
      else if ((i - ba == 3) || (ba - i == 3)) ph = ph3;
      else                                     ph = ph2;
      selfSum = __builtin_fmaf(ci, ph, selfSum);
      if (i == ba) ca = ci;
    }
    s_self[tid] = KCOUL * selfSum;
    s_feat[tid] = KCOUL * __builtin_fmaf(ca, diag, tot);
  }
  __syncthreads();

  // ---- projection + write (map sorted node -> original id) ----
  if (tid < 256) {
    const int node = tid >> 4;           // sorted-space node within block
    const int k    = tid & 15;
    const int m    = g * 128 + s_orig[nb * 16 + node];
    float vf = project_one(&s_feat[node * 28], k);
    float vs = project_one(&s_self[node * 28], k);
    out[m * 16 + k]             = vf;
    out[MTOT * 16 + m * 16 + k] = vs;
  }
}

} // namespace

extern "C" void kernel_launch(void* const* d_in, const int* in_sizes, int n_in,
                              void* d_out, int out_size, void* d_ws, size_t ws_size,
                              hipStream_t stream) {
  const float* sf  = (const float*)d_in[0];   // source_feats (4096,1,4)
  const float* pos = (const float*)d_in[1];   // node_positions (4096,3)
  float* out = (float*)d_out;
  es_main<<<256, 896, 0, stream>>>(sf, pos, out);
}

// Round 14
// 70.339 us; speedup vs baseline: 1.3855x; 1.0692x over previous
//
#include <hip/hip_runtime.h>
#include <math.h>

namespace {

constexpr int   MTOT = 4096;       // total nodes
constexpr float H    = 0.1f;

// W_FACTORS = sqrt((0.5^2 + sigma^2)/2), sigma in {0.4, 0.8, 1.2, 1.6}
constexpr float W0 = 0.45276925690687087f;
constexpr float W1 = 0.66708320320631664f;
constexpr float W2 = 0.91923881554251174f;
constexpr float W3 = 1.18532695911296985f;

constexpr float KCOUL   = 14.399645478425669f;  // e*1e10/eps0/(4*pi)
constexpr float HALF_L1 = 2.8867513459481287f;  // 0.5*sqrt(3)/0.3
constexpr float SQRTPI  = 1.7724538509055159f;
constexpr float TWOSQPI = 1.1283791670955126f;  // 2/sqrt(pi)

// k_r = 0.5/W_r
constexpr float K0 = 1.1043153f, K1 = 0.74953184f, K2 = 0.54392830f, K3 = 0.42182454f;

// epilogue erf (A&S 7.1.25, |err|<=2.5e-5): pk=0.47047*k, c2=-k^2*log2e
constexpr float PK0 = 0.5195472f, PK1 = 0.3526314f, PK2 = 0.2559019f, PK3 = 0.1984558f;
constexpr float C20 = -1.7593842f, C21 = -0.8105028f, C22 = -0.4268329f, C23 = -0.2567073f;
constexpr float EA1 = 0.3480242f, EA2 = -0.0958798f, EA3 = 0.7478556f;
constexpr float RCP_H = 9.9999000f, RCP_HS2 = 7.0710178f, RCP_2H = 4.9999750f;

// erf lookup table: 512 entries over d in [0, 7.68), h = 0.015
constexpr int   TABN  = 512;
constexpr float TAB_H = 0.015f;
constexpr float INV_H = 66.666664f;

// g/Gt tables (dipole tier): 256 entries, h = 0.03, same range
constexpr int   TGN   = 256;
constexpr float TG_H  = 0.03f;
constexpr float INV_G = 33.333332f;

// tier radii: near if any lane d<2; saturated (all erf==1) if all lanes d>7.03
constexpr float NEAR2 = 4.0f;
constexpr float SAT2  = 49.4f;

__device__ __forceinline__ float fast_rcp(float x)  { return __builtin_amdgcn_rcpf(x); }
__device__ __forceinline__ float fast_rsq(float x)  { return __builtin_amdgcn_rsqf(x); }
__device__ __forceinline__ float fast_exp2(float x) { return __builtin_amdgcn_exp2f(x); }

// epilogue: q = erfc-part of A&S 7.1.25
__device__ __forceinline__ float erf_q(float d, float d2, float pk, float c2) {
  float t = fast_rcp(__builtin_fmaf(d, pk, 1.0f));
  float poly = t * __builtin_fmaf(t, __builtin_fmaf(t, EA3, EA2), EA1);
  return poly * fast_exp2(d2 * c2);
}

// project (7 x 4) site-features S[j*4+r] -> 16 outputs
__device__ __forceinline__ float project_one(const float* S, int k) {
  if (k < 4) return S[k];
  int q = k - 4;
  int r = q / 3;
  int comp = q - 3 * r;
  int j1, j2;
  if (comp == 0)      { j1 = 2; j2 = 5; }
  else if (comp == 1) { j1 = 3; j2 = 6; }
  else                { j1 = 1; j2 = 4; }
  return HALF_L1 * (S[j1 * 4 + r] - S[j2 * 4 + r]);
}

__device__ __forceinline__ unsigned spread3(int v) {
  return (unsigned)((v & 1) | ((v & 2) << 2) | ((v & 4) << 4));
}

// grid: 256 blocks = 32 graphs x 8 node-blocks; block: 896 thr = 112 sites x 8 chunks.
// Morton-sorted nodes; 3-tier source loop: near=exact 7-site table path,
// mid=monopole+dipole with g/Gt tables, sat=analytic monopole+dipole (g=1/d).
__global__ __launch_bounds__(896, 4) void es_main(
    const float* __restrict__ sf,   // (4096, 4)
    const float* __restrict__ pos,  // (4096, 3)
    float* __restrict__ out)        // [0:65536) features, [65536:131072) self_terms
{
  __shared__ float4   s_pos4[128];     // node centers (SORTED)
  __shared__ float4   s_chg4[128];     // prescaled charges {s0,5s3,5s1,5s2} (SORTED)
  __shared__ int      s_orig[128];     // sorted slot -> original node
  __shared__ unsigned s_key[128];
  __shared__ float4   s_tabV[TABN];    // erf values (r0..r3)
  __shared__ float4   s_tabD[TABN];    // erf per-cell deltas
  __shared__ float4   s_gV[TGN], s_gD[TGN];   // g = erf(kd)/d, value+delta
  __shared__ float4   s_tV[TGN], s_tD[TGN];   // Gt = -0.2 g'/d, value+delta
  __shared__ __align__(16) char s_u[8 * 112 * 16];  // union: erf raw build | s_part
  __shared__ float    s_feat[448];
  __shared__ float    s_self[448];

  float (*s_tmp)[TABN + 1] = reinterpret_cast<float (*)[TABN + 1]>(s_u);  // [4][513]
  float4* s_part = reinterpret_cast<float4*>(s_u);                        // [8*112]

  const int b   = blockIdx.x;
  const int g   = b >> 3;    // graph
  const int nb  = b & 7;     // node-block (sorted space)
  const int tid = threadIdx.x;

  // ---- phase 1: node data + keys; erf raw; g/Gt tables ----
  float px = 0.f, py = 0.f, pz = 0.f;
  float4 myc = make_float4(0.f, 0.f, 0.f, 0.f);
  if (tid < 128) {
    const float* p = pos + (size_t)(g * 128 + tid) * 3;
    px = p[0]; py = p[1]; pz = p[2];
    const float4 s = ((const float4*)sf)[g * 128 + tid];
    myc = make_float4(s.x, 5.0f * s.w, 5.0f * s.y, 5.0f * s.z);
    int cx = (int)((px + 16.0f) * 0.25f); cx = (cx < 0) ? 0 : (cx > 7 ? 7 : cx);
    int cy = (int)((py + 16.0f) * 0.25f); cy = (cy < 0) ? 0 : (cy > 7 ? 7 : cy);
    int cz = (int)((pz + 16.0f) * 0.25f); cz = (cz < 0) ? 0 : (cz > 7 ? 7 : cz);
    unsigned mort = spread3(cx) | (spread3(cy) << 1) | (spread3(cz) << 2);
    s_key[tid] = (mort << 7) | (unsigned)tid;
  }
  if (tid <= TABN) {
    const float d = tid * TAB_H;
    s_tmp[0][tid] = erff(K0 * d);
    s_tmp[1][tid] = erff(K1 * d);
    s_tmp[2][tid] = erff(K2 * d);
    s_tmp[3][tid] = erff(K3 * d);
  }
  if (tid >= 640) {                      // 256 threads build g/Gt tables
    const int e = tid - 640;             // 0..255 (entries below d=2 unused)
    const float d0 = fmaxf(e * TG_H, 1e-3f);
    const float d1 = (e + 1) * TG_H;
    const float ks[4] = {K0, K1, K2, K3};
    float gv[4], gd[4], tv[4], td[4];
#pragma unroll
    for (int r = 0; r < 4; ++r) {
      const float k = ks[r];
      const float e0 = erff(k * d0), e1 = erff(k * d1);
      const float x0 = expf(-k * k * d0 * d0), x1 = expf(-k * k * d1 * d1);
      const float g0 = e0 / d0, g1 = e1 / d1;
      const float t0 = 0.2f * e0 / (d0 * d0 * d0) - 0.2f * TWOSQPI * k * x0 / (d0 * d0);
      const float t1 = 0.2f * e1 / (d1 * d1 * d1) - 0.2f * TWOSQPI * k * x1 / (d1 * d1);
      gv[r] = g0; gd[r] = g1 - g0; tv[r] = t0; td[r] = t1 - t0;
    }
    s_gV[e] = make_float4(gv[0], gv[1], gv[2], gv[3]);
    s_gD[e] = make_float4(gd[0], gd[1], gd[2], gd[3]);
    s_tV[e] = make_float4(tv[0], tv[1], tv[2], tv[3]);
    s_tD[e] = make_float4(td[0], td[1], td[2], td[3]);
  }
  __syncthreads();

  // ---- phase 2: rank-sort scatter; pack erf tables ----
  if (tid < 128) {
    const unsigned mykey = s_key[tid];
    int rank = 0;
    for (int t = 0; t < 128; ++t) rank += (s_key[t] < mykey) ? 1 : 0;
    s_pos4[rank] = make_float4(px, py, pz, 0.0f);
    s_chg4[rank] = myc;
    s_orig[rank] = tid;
  }
  if (tid < TABN) {
    const float v0 = s_tmp[0][tid], v1 = s_tmp[1][tid];
    const float v2v = s_tmp[2][tid], v3 = s_tmp[3][tid];
    s_tabV[tid] = make_float4(v0, v1, v2v, v3);
    s_tabD[tid] = make_float4(s_tmp[0][tid + 1] - v0, s_tmp[1][tid + 1] - v1,
                              s_tmp[2][tid + 1] - v2v, s_tmp[3][tid + 1] - v3);
  }
  __syncthreads();

  // ---- per-thread target site (sorted space) ----
  const int site_local = tid % 112;
  const int chunk      = tid / 112;          // 0..7, 16 source nodes each
  const int sl   = nb * 112 + site_local;
  const int jown = (sl * 9363) >> 16;        // own node slot
  const int aoff = sl - jown * 7;

  const float4 cp = s_pos4[jown];
  const float tx = cp.x + ((aoff == 1) ? H : (aoff == 4) ? -H : 0.0f);
  const float ty = cp.y + ((aoff == 2) ? H : (aoff == 5) ? -H : 0.0f);
  const float tz = cp.z + ((aoff == 3) ? H : (aoff == 6) ? -H : 0.0f);

  float a0 = 0.f, a1 = 0.f, a2 = 0.f, a3 = 0.f, Ssat = 0.f;

  auto acc_full = [&](float d2raw, float c) {
    float d2 = fmaxf(d2raw, 1e-12f);
    float rd = fast_rsq(d2);
    float cv = c * rd;
    float t  = (d2 * rd) * INV_H;
    int  idx = (int)t;
    float f  = t - (float)idx;
    idx = (idx < TABN - 1) ? idx : (TABN - 1);
    f = fminf(f, 1.0f);
    const float4 V = s_tabV[idx];
    const float4 D = s_tabD[idx];
    a0 = __builtin_fmaf(cv, __builtin_fmaf(D.x, f, V.x), a0);
    a1 = __builtin_fmaf(cv, __builtin_fmaf(D.y, f, V.y), a1);
    a2 = __builtin_fmaf(cv, __builtin_fmaf(D.z, f, V.z), a2);
    a3 = __builtin_fmaf(cv, __builtin_fmaf(D.w, f, V.w), a3);
  };

  const int j0 = chunk * 16;
  for (int jj = 0; jj < 16; ++jj) {
    const int j = j0 + jj;
    const float4 p4 = s_pos4[j];
    const float4 c4 = s_chg4[j];
    const float vx = tx - p4.x;
    const float vy = ty - p4.y;
    const float vz = tz - p4.z;
    const float v2 = __builtin_fmaf(vx, vx, __builtin_fmaf(vy, vy, vz * vz));
    if (__any(v2 < NEAR2)) {
      // NEAR: exact 7-site path (valid at all d); own-site masking
      const float w2 = v2 + 0.01f;
      const bool own = (j == jown);
      acc_full(v2,                            (own & (aoff == 0)) ? 0.0f :  c4.x);
      acc_full(__builtin_fmaf(vx, -0.2f, w2), (own & (aoff == 1)) ? 0.0f :  c4.y);
      acc_full(__builtin_fmaf(vy, -0.2f, w2), (own & (aoff == 2)) ? 0.0f :  c4.z);
      acc_full(__builtin_fmaf(vz, -0.2f, w2), (own & (aoff == 3)) ? 0.0f :  c4.w);
      acc_full(__builtin_fmaf(vx,  0.2f, w2), (own & (aoff == 4)) ? 0.0f : -c4.y);
      acc_full(__builtin_fmaf(vy,  0.2f, w2), (own & (aoff == 5)) ? 0.0f : -c4.z);
      acc_full(__builtin_fmaf(vz,  0.2f, w2), (own & (aoff == 6)) ? 0.0f : -c4.w);
    } else if (__any(v2 < SAT2)) {
      // MID: all lanes d>=2 -> monopole + dipole via g/Gt tables (per-lane sat fallback)
      const float rd  = fast_rsq(v2);
      const float d   = v2 * rd;
      const float dot = __builtin_fmaf(c4.y, vx, __builtin_fmaf(c4.z, vy, c4.w * vz));
      const float t   = d * INV_G;
      const int   idx = (int)t;
      const bool  in  = (idx < TGN - 1);
      const int   ic  = in ? idx : (TGN - 2);
      const float f   = fminf(t - (float)idx, 1.0f);
      const float4 Gv = s_gV[ic], Gd = s_gD[ic];
      const float4 Tv = s_tV[ic], Td = s_tD[ic];
      const float rd2 = rd * rd;
      const float gs  = rd;                // saturated g = 1/d
      const float ts  = 0.2f * rd2 * rd;   // saturated Gt = 0.2/d^3
      const float g0v = in ? __builtin_fmaf(Gd.x, f, Gv.x) : gs;
      const float g1v = in ? __builtin_fmaf(Gd.y, f, Gv.y) : gs;
      const float g2v = in ? __builtin_fmaf(Gd.z, f, Gv.z) : gs;
      const float g3v = in ? __builtin_fmaf(Gd.w, f, Gv.w) : gs;
      const float t0v = in ? __builtin_fmaf(Td.x, f, Tv.x) : ts;
      const float t1v = in ? __builtin_fmaf(Td.y, f, Tv.y) : ts;
      const float t2v = in ? __builtin_fmaf(Td.z, f, Tv.z) : ts;
      const float t3v = in ? __builtin_fmaf(Td.w, f, Tv.w) : ts;
      a0 = __builtin_fmaf(c4.x, g0v, __builtin_fmaf(dot, t0v, a0));
      a1 = __builtin_fmaf(c4.x, g1v, __builtin_fmaf(dot, t1v, a1));
      a2 = __builtin_fmaf(c4.x, g2v, __builtin_fmaf(dot, t2v, a2));
      a3 = __builtin_fmaf(c4.x, g3v, __builtin_fmaf(dot, t3v, a3));
    } else {
      // SAT: all lanes fully saturated -> analytic monopole + dipole
      const float rd  = fast_rsq(v2);
      const float dot = __builtin_fmaf(c4.y, vx, __builtin_fmaf(c4.z, vy, c4.w * vz));
      Ssat = __builtin_fmaf(c4.x, rd, Ssat);
      Ssat = __builtin_fmaf(0.2f * dot, rd * rd * rd, Ssat);
    }
  }
  a0 += Ssat; a1 += Ssat; a2 += Ssat; a3 += Ssat;

  s_part[chunk * 112 + site_local] = make_float4(a0, a1, a2, a3);
  __syncthreads();

  // ---- reduce chunks + self term + own-node correction (cancels to +c_a*diag) ----
  if (tid < 448) {
    const int site = tid >> 2;   // 0..111 (sorted space)
    const int r    = tid & 3;
    const float* pf = (const float*)s_part;
    float tot = 0.f;
#pragma unroll
    for (int c = 0; c < 8; ++c) tot += pf[c * 448 + tid];

    const float w  = (r == 0) ? W0  : (r == 1) ? W1  : (r == 2) ? W2  : W3;
    const float pk = (r == 0) ? PK0 : (r == 1) ? PK1 : (r == 2) ? PK2 : PK3;
    const float c2 = (r == 0) ? C20 : (r == 1) ? C21 : (r == 2) ? C22 : C23;
    const float diag = fast_rcp(w * SQRTPI);
    const float ph1 = (1.f - erf_q(0.1f,        0.01f, pk, c2)) * RCP_H;
    const float ph2 = (1.f - erf_q(0.14142136f, 0.02f, pk, c2)) * RCP_HS2;
    const float ph3 = (1.f - erf_q(0.2f,        0.04f, pk, c2)) * RCP_2H;

    const int jn = (site * 9363) >> 16;
    const int ba = site - jn * 7;
    const float4 c4 = s_chg4[nb * 16 + jn];
    float selfSum = 0.f, ca = 0.f;
#pragma unroll
    for (int i = 0; i < 7; ++i) {
      const float ci = (i == 0) ?  c4.x : (i == 1) ?  c4.y : (i == 2) ?  c4.z :
                       (i == 3) ?  c4.w : (i == 4) ? -c4.y : (i == 5) ? -c4.z : -c4.w;
      float ph;
      if (i == ba)                             ph = diag;
      else if (i == 0 || ba == 0)              ph = ph1;
      else if ((i - ba == 3) || (ba - i == 3)) ph = ph3;
      else                                     ph = ph2;
      selfSum = __builtin_fmaf(ci, ph, selfSum);
      if (i == ba) ca = ci;
    }
    s_self[tid] = KCOUL * selfSum;
    s_feat[tid] = KCOUL * __builtin_fmaf(ca, diag, tot);
  }
  __syncthreads();

  // ---- projection + write (map sorted node -> original id) ----
  if (tid < 256) {
    const int node = tid >> 4;
    const int k    = tid & 15;
    const int m    = g * 128 + s_orig[nb * 16 + node];
    float vf = project_one(&s_feat[node * 28], k);
    float vs = project_one(&s_self[node * 28], k);
    out[m * 16 + k]             = vf;
    out[MTOT * 16 + m * 16 + k] = vs;
  }
}

} // namespace

extern "C" void kernel_launch(void* const* d_in, const int* in_sizes, int n_in,
                              void* d_out, int out_size, void* d_ws, size_t ws_size,
                              hipStream_t stream) {
  const float* sf  = (const float*)d_in[0];   // source_feats (4096,1,4)
  const float* pos = (const float*)d_in[1];   // node_positions (4096,3)
  float* out = (float*)d_out;
  es_main<<<256, 896, 0, stream>>>(sf, pos, out);
}